// Round 11
// baseline (432.958 us; speedup 1.0000x reference)
//
#include <hip/hip_runtime.h>
#include <math.h>

typedef unsigned short u16;
typedef __bf16 bf16_t;
typedef u16 u16x4 __attribute__((ext_vector_type(4)));
typedef u16 u16x8 __attribute__((ext_vector_type(8)));
typedef bf16_t bf16x8 __attribute__((ext_vector_type(8)));
typedef float f32x4 __attribute__((ext_vector_type(4)));

__device__ __forceinline__ float bf2f(u16 v) {
    union { unsigned u; float f; } x; x.u = ((unsigned)v) << 16; return x.f;
}
// Manual RNE f32->bf16 (exact baseline-522 behavior).
__device__ __forceinline__ u16 f2bf(float f) {
    union { float f; unsigned u; } x; x.f = f;
    unsigned u = x.u;
    return (u16)((u + 0x7fffu + ((u >> 16) & 1u)) >> 16);
}

// Async global->LDS DMA, 16B per lane. LDS dest = wave-uniform base + lane*16
// (hardware-defined); global src is per-lane.
__device__ __forceinline__ void gload16(const u16* g, u16* l) {
    __builtin_amdgcn_global_load_lds(
        (const __attribute__((address_space(1))) void*)g,
        (__attribute__((address_space(3))) void*)l,
        16, 0, 0);
}

// Units whose f32 partial-O lives in the dead ws region; the rest overlay d_out.
#define POWS_UNITS 436

// ---------------------------------------------------------------------------
// Runtime dtype detector (probe = Wq). bf16: high byte of each u32 is sign/exp
// in [0x38,0x3F]; fp32: uniform mantissa byte. 64-lane majority => exact.
// ---------------------------------------------------------------------------
__device__ __forceinline__ bool is_bf16_input(const unsigned* __restrict__ probe) {
    unsigned w = probe[(threadIdx.x & 63) * 32771 + 7];
    unsigned b7 = (w >> 8) & 0x7f;
    bool hit = (b7 >= 0x38) && (b7 <= 0x3f);
    return __builtin_popcountll(__ballot(hit)) >= 32;
}

// ---------------------------------------------------------------------------
// Merged prep: blocks [0,4096) convert X; [4096,8192) transpose Wq;
// [8192,9216) transpose Wk; [9216,10240) transpose Wv. One launch instead of
// four (launch/drain gaps ~5-8 us each on this harness).
// ---------------------------------------------------------------------------
__global__ __launch_bounds__(256) void prep_kernel(
    const void* __restrict__ X, u16* __restrict__ Xc,
    const void* __restrict__ Wq, const void* __restrict__ Wk,
    const void* __restrict__ Wv, u16* __restrict__ WqkvT,
    const unsigned* __restrict__ probe)
{
    __shared__ u16 t[32][33];
    const bool bf = is_bf16_input(probe);
    const int bid = blockIdx.x;

    if (bid < 4096) {                     // convert X (8388608 elems, exact)
        int i = (bid * 256 + threadIdx.x) * 8;
        if (bf) {
            *(u16x8*)&Xc[i] = *(const u16x8*)&((const u16*)X)[i];
        } else {
            const float* s = (const float*)X + i;
            u16x8 o;
#pragma unroll
            for (int j = 0; j < 8; j++) o[j] = f2bf(s[j]);
            *(u16x8*)&Xc[i] = o;
        }
        return;
    }

    const void* in; u16* out; int R, C, bx, by;
    if (bid < 8192) {        // Wq^T: grid 64x64
        int b2 = bid - 4096; in = Wq; out = WqkvT;
        R = 2048; C = 2048; bx = (b2 & 63) * 32; by = (b2 >> 6) * 32;
    } else if (bid < 9216) { // Wk^T: grid 16x64
        int b2 = bid - 8192; in = Wk; out = WqkvT + 2048 * 2048;
        R = 2048; C = 512; bx = (b2 & 15) * 32; by = (b2 >> 4) * 32;
    } else {                 // Wv^T: grid 16x64
        int b2 = bid - 9216; in = Wv; out = WqkvT + 2560 * 2048;
        R = 2048; C = 512; bx = (b2 & 15) * 32; by = (b2 >> 4) * 32;
    }
    int x = threadIdx.x & 31, y = threadIdx.x >> 5;
    if (bf) {
        const u16* s = (const u16*)in;
#pragma unroll
        for (int i = 0; i < 32; i += 8)
            t[y + i][x] = s[(size_t)(by + y + i) * C + bx + x];
    } else {
        const float* s = (const float*)in;
#pragma unroll
        for (int i = 0; i < 32; i += 8)
            t[y + i][x] = f2bf(s[(size_t)(by + y + i) * C + bx + x]);
    }
    __syncthreads();
#pragma unroll
    for (int i = 0; i < 32; i += 8)
        out[(size_t)(bx + y + i) * R + by + x] = t[x][y + i];
}

__global__ __launch_bounds__(256) void tconv_kernel(
    const void* __restrict__ in, u16* __restrict__ out, int R, int C,
    const unsigned* __restrict__ probe)
{
    bool bf = is_bf16_input(probe);
    __shared__ u16 t[32][33];
    int x = threadIdx.x & 31, y = threadIdx.x >> 5;
    int bx = blockIdx.x * 32, by = blockIdx.y * 32;
    if (bf) {
        const u16* s = (const u16*)in;
#pragma unroll
        for (int i = 0; i < 32; i += 8)
            t[y + i][x] = s[(size_t)(by + y + i) * C + bx + x];
    } else {
        const float* s = (const float*)in;
#pragma unroll
        for (int i = 0; i < 32; i += 8)
            t[y + i][x] = f2bf(s[(size_t)(by + y + i) * C + bx + x]);
    }
    __syncthreads();
#pragma unroll
    for (int i = 0; i < 32; i += 8)
        out[(size_t)(bx + y + i) * R + by + x] = t[x][y + i];
}

// Transpose with separate input row stride (pulls V columns out of fused QKV).
__global__ __launch_bounds__(256) void transpose_kernel(
    const u16* __restrict__ in, u16* __restrict__ out, int R, int LD)
{
    __shared__ u16 t[32][33];
    int x = threadIdx.x & 31, y = threadIdx.x >> 5;
    int bx = blockIdx.x * 32, by = blockIdx.y * 32;
#pragma unroll
    for (int i = 0; i < 32; i += 8)
        t[y + i][x] = in[(size_t)(by + y + i) * LD + bx + x];
    __syncthreads();
#pragma unroll
    for (int i = 0; i < 32; i += 8)
        out[(size_t)(bx + y + i) * R + by + x] = t[x][y + i];
}

// ---------------------------------------------------------------------------
// GEMM: C[M,N] = (A[M,K] @ BT[N,K]^T + bias[N]) * scale
// global_load_lds width=16 staging into linear [128][32] LDS tiles.
// Bias read RAW (bf16/f32 via probe); segmented for the fused-QKV call.
// ---------------------------------------------------------------------------
__global__ __launch_bounds__(256) void gemm_bias_kernel(
    const u16* __restrict__ A, const u16* __restrict__ BT,
    const void* __restrict__ bias0, const void* __restrict__ bias1,
    const void* __restrict__ bias2, void* __restrict__ Cout,
    int M, int N, int K, const unsigned* __restrict__ probe,
    int out_native, float scale)
{
    __shared__ __align__(16) u16 As[128 * 32];
    __shared__ __align__(16) u16 Bs[128 * 32];
    const int tid  = threadIdx.x;
    const int lane = tid & 63, wave = tid >> 6;
    const int quad = lane >> 4, li = lane & 15;
    const int bm = blockIdx.x * 128, bn = blockIdx.y * 128;
    const int wm = (wave >> 1) * 64, wn = (wave & 1) * 64;
    const int lrow = lane >> 2;          // 0..15 row within 16-row chunk
    const int lcol = (lane & 3) * 8;     // u16 col offset

    f32x4 acc[4][4] = {};

    for (int k0 = 0; k0 < K; k0 += 32) {
#pragma unroll
        for (int j = 0; j < 2; j++) {
            int c = wave * 2 + j;
            int row = c * 16 + lrow;
            gload16(&A [(size_t)(bm + row) * K + k0 + lcol], &As[c * 16 * 32]);
            gload16(&BT[(size_t)(bn + row) * K + k0 + lcol], &Bs[c * 16 * 32]);
        }
        __syncthreads();   // vmcnt drained at barrier: tiles ready
        bf16x8 af[4], bfr[4];
#pragma unroll
        for (int i = 0; i < 4; i++)
            af[i]  = *(const bf16x8*)&As[(wm + i * 16 + li) * 32 + quad * 8];
#pragma unroll
        for (int i = 0; i < 4; i++)
            bfr[i] = *(const bf16x8*)&Bs[(wn + i * 16 + li) * 32 + quad * 8];
#pragma unroll
        for (int mt = 0; mt < 4; mt++)
#pragma unroll
            for (int nt = 0; nt < 4; nt++)
                acc[mt][nt] = __builtin_amdgcn_mfma_f32_16x16x32_bf16(
                    af[mt], bfr[nt], acc[mt][nt], 0, 0, 0);
        __syncthreads();
    }

    const bool bf_in = is_bf16_input(probe);
    const bool out_bf = out_native ? bf_in : true;
#pragma unroll
    for (int nt = 0; nt < 4; nt++) {
        int col = bn + wn + nt * 16 + li;
        const void* bp; int bc;
        if (col < 2048)      { bp = bias0; bc = col; }
        else if (col < 2560) { bp = bias1; bc = col - 2048; }
        else                 { bp = bias2; bc = col - 2560; }
        float bb = bf_in ? bf2f(((const u16*)bp)[bc]) : ((const float*)bp)[bc];
        if (out_bf) {
            u16* C16 = (u16*)Cout;
#pragma unroll
            for (int mt = 0; mt < 4; mt++)
#pragma unroll
                for (int r = 0; r < 4; r++) {
                    int row = bm + wm + mt * 16 + quad * 4 + r;
                    C16[(size_t)row * N + col] = f2bf((acc[mt][nt][r] + bb) * scale);
                }
        } else {
            float* Cf = (float*)Cout;
#pragma unroll
            for (int mt = 0; mt < 4; mt++)
#pragma unroll
                for (int r = 0; r < 4; r++) {
                    int row = bm + wm + mt * 16 + quad * 4 + r;
                    Cf[(size_t)row * N + col] = (acc[mt][nt][r] + bb) * scale;
                }
        }
    }
}

// ---------------------------------------------------------------------------
// Flash attention v12 = v11 balanced split-key, V read DIRECT from global.
// Round-10 analysis: flash floor ~85us + 1.46us/crit-iter; at 4 resident
// blocks/CU the per-iter LDS traffic (K+V staging writes, K/V/P reads
// ~1250cy/block-iter x4 blocks) saturates the LDS pipe -> chain stretch
// ~2.2x. V is read ONCE per wave per tile and VT (~4MB) is L2-resident with
// ~108-block reuse per (b,g) -> V staging is pure LDS overhead (guide
// common-mistake #7). PV now loads vf directly from VT (v4's addressing,
// correctness-proven); K staging + barriers + P round-trip byte-identical.
// LDS 29184 -> 18944 B; V LDS writes+reads eliminated (~40% LDS traffic).
// Schedule unchanged: qt 0..6 unsplit, qt 7..13 x2, qt 14..15 x3; 864 blocks.
// Q:[B*S,3072]  K:[B*S,3072]@+2048  VT:[512,B*S]  O:[B*S,2048].
// ---------------------------------------------------------------------------
__global__ __launch_bounds__(256) void flash_kernel(
    const u16* __restrict__ Q, const u16* __restrict__ Kg,
    const u16* __restrict__ VT, u16* __restrict__ O,
    float* __restrict__ POws, float* __restrict__ POdout,
    float* __restrict__ PM, float* __restrict__ PL)
{
    constexpr int S = 2048, D = 2048, DH = 128, QKSTR = 3072;
    constexpr float SCALE = 0.08838834764831845f;  // 1/sqrt(128)
    __shared__ __align__(16) u16 Ks[32 * 136];   // [key][dh]   8704 B
    __shared__ __align__(16) u16 Pw[4][32 * 40]; // [qrow][key] 10240 B

    const int tid  = threadIdx.x;
    const int wave = tid >> 6, lane = tid & 63;
    const int quad = lane >> 4, li = lane & 15;
    const int uu = blockIdx.x, h = blockIdx.y, b = blockIdx.z;
    // unit decode: uu 0..6 -> unsplit qt=uu; uu 7..20 -> qt 7..13 x2 chunks;
    // uu 21..26 -> qt 14..15 x3 chunks. Chunk = near-equal tile count.
    int qt, cc, nc;
    if (uu < 7)       { qt = uu;                         cc = 0;          nc = 1; }
    else if (uu < 21) { int t = uu - 7;  qt = 7 + (t >> 1);  cc = t & 1;  nc = 2; }
    else              { int t = uu - 21; qt = 14 + t / 3;    cc = t % 3;  nc = 3; }
    const int T = qt + 1;                 // tiles (128 keys each)
    const int tb = T / nc, trem = T % nc;
    const int tcnt = tb + (cc < trem ? 1 : 0);
    const int tstart = cc * tb + (cc < trem ? cc : trem);
    const int kstart = tstart * 128;
    const int kend   = (tstart + tcnt) * 128;
    const int g = h >> 2;
    const int q0w = qt * 128 + wave * 32;        // this wave's first q-row

    const u16* Qb = Q  + (size_t)b * S * QKSTR;
    const u16* Kb = Kg + (size_t)b * S * QKSTR;
    const u16* Vg = VT + (size_t)g * DH * (2 * S) + (size_t)b * S;

    // Q fragments: B-operand, rows q0w + m*16 + li, k = quad*8 (+c*32)
    bf16x8 qf[2][4];
#pragma unroll
    for (int m = 0; m < 2; m++)
#pragma unroll
        for (int c = 0; c < 4; c++)
            qf[m][c] = *(const bf16x8*)&Qb[(size_t)(q0w + m * 16 + li) * QKSTR
                                           + h * DH + c * 32 + quad * 8];

    f32x4 oacc[2][8] = {};
    float mr[2] = { -INFINITY, -INFINITY };
    float lr[2] = { 0.f, 0.f };

    // --- register prefetch of K tile at kstart ---
    u16x8 kreg[2];
#pragma unroll
    for (int ch = 0; ch < 2; ch++) {
        int idx = tid + ch * 256;
        kreg[ch] = *(const u16x8*)&Kb[(size_t)(kstart + (idx >> 4)) * QKSTR
                                      + g * DH + (idx & 15) * 8];
    }

    for (int kc = kstart; kc < kend; kc += 32) {
        // commit prefetched K tile to LDS
#pragma unroll
        for (int ch = 0; ch < 2; ch++) {
            int idx = tid + ch * 256;
            *(u16x8*)&Ks[(idx >> 4) * 136 + (idx & 15) * 8] = kreg[ch];
        }
        __syncthreads();

        // issue K prefetch for next tile (overlaps with compute below)
        int kn = kc + 32;
        if (kn < kend) {
#pragma unroll
            for (int ch = 0; ch < 2; ch++) {
                int idx = tid + ch * 256;
                kreg[ch] = *(const u16x8*)&Kb[(size_t)(kn + (idx >> 4)) * QKSTR
                                              + g * DH + (idx & 15) * 8];
            }
        }

        if (kc <= q0w) {   // causal: tiles with kc > q0w are fully masked
            // S^T = K · Q^T : sacc[m][t], C row = key (quad*4+r), col = qrow (li)
            f32x4 sacc[2][2] = {};
#pragma unroll
            for (int t = 0; t < 2; t++)
#pragma unroll
                for (int c = 0; c < 4; c++) {
                    bf16x8 kf = *(const bf16x8*)&Ks[(t * 16 + li) * 136 + c * 32 + quad * 8];
#pragma unroll
                    for (int m = 0; m < 2; m++)
                        sacc[m][t] = __builtin_amdgcn_mfma_f32_16x16x32_bf16(
                            kf, qf[m][c], sacc[m][t], 0, 0, 0);
                }

            float alpha_b[2][4];
#pragma unroll
            for (int m = 0; m < 2; m++) {
                int row = q0w + m * 16 + li;
                f32x4 s0 = sacc[m][0] * SCALE;
                f32x4 s1 = sacc[m][1] * SCALE;
#pragma unroll
                for (int r = 0; r < 4; r++) {
                    int k0 = kc + quad * 4 + r;
                    if (k0 > row)      s0[r] = -INFINITY;
                    if (k0 + 16 > row) s1[r] = -INFINITY;
                }
                float mx = fmaxf(fmaxf(fmaxf(s0[0], s0[1]), fmaxf(s0[2], s0[3])),
                                 fmaxf(fmaxf(s1[0], s1[1]), fmaxf(s1[2], s1[3])));
                mx = fmaxf(mx, __shfl_xor(mx, 16));
                mx = fmaxf(mx, __shfl_xor(mx, 32));
                float mnew = fmaxf(mr[m], mx);
                float al = __expf(mr[m] - mnew);
                mr[m] = mnew;
                f32x4 p0, p1;
                float ps = 0.f;
#pragma unroll
                for (int r = 0; r < 4; r++) {
                    p0[r] = __expf(s0[r] - mnew);
                    p1[r] = __expf(s1[r] - mnew);
                    ps += p0[r] + p1[r];
                }
                ps += __shfl_xor(ps, 16);
                ps += __shfl_xor(ps, 32);
                lr[m] = lr[m] * al + ps;
                u16x4 c0, c1;
#pragma unroll
                for (int r = 0; r < 4; r++) { c0[r] = f2bf(p0[r]); c1[r] = f2bf(p1[r]); }
                *(u16x4*)&Pw[wave][(m * 16 + li) * 40 + quad * 4]      = c0;
                *(u16x4*)&Pw[wave][(m * 16 + li) * 40 + 16 + quad * 4] = c1;
#pragma unroll
                for (int r = 0; r < 4; r++)
                    alpha_b[m][r] = __shfl(al, quad * 4 + r, 16);
            }

            // rescale O accumulators
#pragma unroll
            for (int m = 0; m < 2; m++)
#pragma unroll
                for (int dt = 0; dt < 8; dt++)
#pragma unroll
                    for (int r = 0; r < 4; r++)
                        oacc[m][dt][r] *= alpha_b[m][r];

            // drain P stores (same wave) before vector re-read
            asm volatile("s_waitcnt lgkmcnt(0)" ::: "memory");
            union { u16x8 u; bf16x8 bv; } pc0, pc1;
            pc0.u = *(const u16x8*)&Pw[wave][(0 * 16 + li) * 40 + quad * 8];
            pc1.u = *(const u16x8*)&Pw[wave][(1 * 16 + li) * 40 + quad * 8];
            bf16x8 pf[2] = { pc0.bv, pc1.bv };

            // O += P · V   (V fragments DIRECT from global VT: L2-resident,
            // read once per wave per tile -- staging it in LDS was pure
            // LDS-pipe overhead at 4 resident blocks/CU)
#pragma unroll
            for (int dt = 0; dt < 8; dt++) {
                bf16x8 vf = *(const bf16x8*)&Vg[(size_t)(dt * 16 + li) * (2 * S)
                                                + kc + quad * 8];
#pragma unroll
                for (int m = 0; m < 2; m++)
                    oacc[m][dt] = __builtin_amdgcn_mfma_f32_16x16x32_bf16(
                        pf[m], vf, oacc[m][dt], 0, 0, 0);
            }
        }
        __syncthreads();
    }

    if (nc == 1) {
        u16* Ob = O + (size_t)b * S * D;
#pragma unroll
        for (int m = 0; m < 2; m++) {
#pragma unroll
            for (int r = 0; r < 4; r++) {
                float linv = 1.0f / __shfl(lr[m], quad * 4 + r, 16);
                int row = q0w + m * 16 + quad * 4 + r;
#pragma unroll
                for (int dt = 0; dt < 8; dt++)
                    Ob[(size_t)row * D + h * DH + dt * 16 + li] =
                        f2bf(oacc[m][dt][r] * linv);
            }
        }
    } else {
        // partial epilogue: unnormalized O (f32) + per-row m, l.
        // punit local layout: qt 7..13 -> (qt-7)*2+cc (0..13);
        //                     qt 14..15 -> 14+(qt-14)*3+cc (14..19).
        const int pl = (qt <= 13) ? (qt - 7) * 2 + cc : 14 + (qt - 14) * 3 + cc;
        const int pg = (b * 16 + h) * 20 + pl;
        float* POu = (pg < POWS_UNITS)
                   ? (POws   + (size_t)pg * 16384)
                   : (POdout + (size_t)(pg - POWS_UNITS) * 16384);
#pragma unroll
        for (int m = 0; m < 2; m++)
#pragma unroll
            for (int r = 0; r < 4; r++) {
                int rl = wave * 32 + m * 16 + quad * 4 + r;
#pragma unroll
                for (int dt = 0; dt < 8; dt++)
                    POu[rl * 128 + dt * 16 + li] = oacc[m][dt][r];
            }
        if (quad == 0) {
#pragma unroll
            for (int m = 0; m < 2; m++) {
                int rl = wave * 32 + m * 16 + li;   // mr/lr are per-li rows
                PM[pg * 128 + rl] = mr[m];
                PL[pg * 128 + rl] = lr[m];
            }
        }
    }
}

// ---------------------------------------------------------------------------
// Merge the nc key-chunk partials of each split q-tile (qt 7..15):
// O = sum_i e^{m_i-M} O_i / sum_i e^{m_i-M} l_i.
// Grid (9, 16, 2) x 256 thr; thread -> (row = t>>1, col-half = (t&1)*64).
// ---------------------------------------------------------------------------
__global__ __launch_bounds__(256) void combine_kernel(
    const float* __restrict__ POws, const float* __restrict__ POdout,
    const float* __restrict__ PM, const float* __restrict__ PL,
    u16* __restrict__ O)
{
    constexpr int S = 2048, D = 2048;
    const int qt = 7 + blockIdx.x, h = blockIdx.y, b = blockIdx.z;
    const int nc = (qt <= 13) ? 2 : 3;
    const int pl0 = (qt <= 13) ? (qt - 7) * 2 : 14 + (qt - 14) * 3;
    const int pg0 = (b * 16 + h) * 20 + pl0;
    const int t = threadIdx.x;
    const int row = t >> 1, half = (t & 1) * 64;

    float m[3], l[3], w[3];
    const float* p[3];
    float M = -INFINITY;
    for (int i = 0; i < nc; i++) {
        int pg = pg0 + i;
        m[i] = PM[pg * 128 + row];
        l[i] = PL[pg * 128 + row];
        M = fmaxf(M, m[i]);
        p[i] = ((pg < POWS_UNITS)
                ? (POws   + (size_t)pg * 16384)
                : (POdout + (size_t)(pg - POWS_UNITS) * 16384))
               + row * 128 + half;
    }
    float lsum = 0.f;
    for (int i = 0; i < nc; i++) { w[i] = __expf(m[i] - M); lsum += w[i] * l[i]; }
    float linv = 1.0f / lsum;

    u16* out = O + (size_t)(b * S + qt * 128 + row) * D + h * 128 + half;
#pragma unroll 4
    for (int j = 0; j < 64; j += 4) {
        f32x4 acc = {};
        for (int i = 0; i < nc; i++) {
            f32x4 a = *(const f32x4*)&p[i][j];
#pragma unroll
            for (int e = 0; e < 4; e++) acc[e] += a[e] * w[i];
        }
        u16x4 o;
#pragma unroll
        for (int e = 0; e < 4; e++) o[e] = f2bf(acc[e] * linv);
        *(u16x4*)&out[j] = o;
    }
}

// ---------------------------------------------------------------------------
extern "C" void kernel_launch(void* const* d_in, const int* in_sizes, int n_in,
                              void* d_out, int out_size, void* d_ws, size_t ws_size,
                              hipStream_t stream)
{
    const void* X  = d_in[0];
    const void* Wq = d_in[3];
    const void* bq = d_in[4];
    const void* Wk = d_in[5];
    const void* bk = d_in[6];
    const void* Wv = d_in[7];
    const void* bv = d_in[8];
    const void* Wo = d_in[9];
    const void* bo = d_in[10];
    const unsigned* probe = (const unsigned*)d_in[3];

    u16* ws    = (u16*)d_ws;
    u16* Xc    = ws;                     // [0, 8388608)        X bf16
    u16* WqkvT = Xc    + 8388608;        // [8388608, 14680064) Wqkv^T / later WoT
    u16* QKV   = WqkvT + 6291456;        // [14680064, 27262976)
    u16* VTb   = QKV   + 12582912;       // [27262976, 29360128)
    u16* Ob    = VTb   + 2097152;        // [29360128, 37748736)
    // f32 partials overlay DEAD regions during flash+combine:
    //   POws: 436 units x 16384 f32 in the dead Xc+WqkvT region (7.14M f32)
    //   PM/PL: 640x128 f32 each, after POws (still inside the dead region)
    //   POdout: 204 units x 16384 f32 overlay d_out (written only by the
    //           final GEMM, which runs after combine; fits even bf16 output)
    float* POws   = (float*)ws;
    float* PM     = POws + (size_t)POWS_UNITS * 16384;
    float* PL     = PM + 640 * 128;
    float* POdout = (float*)d_out;

    // Merged prep: convert X + transpose Wq/Wk/Wv (one launch, 10240 blocks)
    prep_kernel<<<10240, 256, 0, stream>>>(X, Xc, Wq, Wk, Wv, WqkvT, probe);

    // Fused QKV projection: grid (32,24) = 768 blocks = 3 blocks/CU.
    gemm_bias_kernel<<<dim3(32, 24), 256, 0, stream>>>(
        Xc, WqkvT, bq, bk, bv, QKV, 4096, 3072, 2048, probe, 0, 1.0f);

    // V columns (2560..3071) of QKV -> VT[512][4096]
    transpose_kernel<<<dim3(16, 128), 256, 0, stream>>>(QKV + 2560, VTb, 4096, 3072);

    // Balanced split-key flash: 27 units x 16 heads x 2 batches = 864 blocks.
    flash_kernel<<<dim3(27, 16, 2), 256, 0, stream>>>(
        QKV, QKV + 2048, VTb, Ob, POws, POdout, PM, PL);

    // Merge split q-tiles (qt 7..15; reads partials, writes Ob).
    combine_kernel<<<dim3(9, 16, 2), 256, 0, stream>>>(POws, POdout, PM, PL, Ob);

    // Wo^T into WqkvT region (partials dead after combine).
    tconv_kernel<<<dim3(64, 64), 256, 0, stream>>>(Wo, WqkvT, 2048, 2048, probe);

    gemm_bias_kernel<<<dim3(32, 16), 256, 0, stream>>>(
        Ob, WqkvT, bo, bo, bo, d_out, 4096, 2048, 2048, probe, 1, 1.0f);
}

// Round 12
// 416.623 us; speedup vs baseline: 1.0392x; 1.0392x over previous
//
#include <hip/hip_runtime.h>
#include <math.h>

typedef unsigned short u16;
typedef __bf16 bf16_t;
typedef u16 u16x4 __attribute__((ext_vector_type(4)));
typedef u16 u16x8 __attribute__((ext_vector_type(8)));
typedef bf16_t bf16x8 __attribute__((ext_vector_type(8)));
typedef float f32x4 __attribute__((ext_vector_type(4)));

__device__ __forceinline__ float bf2f(u16 v) {
    union { unsigned u; float f; } x; x.u = ((unsigned)v) << 16; return x.f;
}
// Manual RNE f32->bf16 (exact baseline-522 behavior).
__device__ __forceinline__ u16 f2bf(float f) {
    union { float f; unsigned u; } x; x.f = f;
    unsigned u = x.u;
    return (u16)((u + 0x7fffu + ((u >> 16) & 1u)) >> 16);
}

// Async global->LDS DMA, 16B per lane. LDS dest = wave-uniform base + lane*16
// (hardware-defined); global src is per-lane.
__device__ __forceinline__ void gload16(const u16* g, u16* l) {
    __builtin_amdgcn_global_load_lds(
        (const __attribute__((address_space(1))) void*)g,
        (__attribute__((address_space(3))) void*)l,
        16, 0, 0);
}

// Units whose f32 partial-O lives in the dead ws region; the rest overlay d_out.
#define POWS_UNITS 436

// ---------------------------------------------------------------------------
// Runtime dtype detector (probe = Wq). bf16: high byte of each u32 is sign/exp
// in [0x38,0x3F]; fp32: uniform mantissa byte. 64-lane majority => exact.
// ---------------------------------------------------------------------------
__device__ __forceinline__ bool is_bf16_input(const unsigned* __restrict__ probe) {
    unsigned w = probe[(threadIdx.x & 63) * 32771 + 7];
    unsigned b7 = (w >> 8) & 0x7f;
    bool hit = (b7 >= 0x38) && (b7 <= 0x3f);
    return __builtin_popcountll(__ballot(hit)) >= 32;
}

// ---------------------------------------------------------------------------
// Merged prep: blocks [0,4096) convert X; [4096,8192) transpose Wq;
// [8192,9216) transpose Wk; [9216,10240) transpose Wv. One launch instead of
// four (launch/drain gaps; measured ~14 us saved, round-11 attribution).
// ---------------------------------------------------------------------------
__global__ __launch_bounds__(256) void prep_kernel(
    const void* __restrict__ X, u16* __restrict__ Xc,
    const void* __restrict__ Wq, const void* __restrict__ Wk,
    const void* __restrict__ Wv, u16* __restrict__ WqkvT,
    const unsigned* __restrict__ probe)
{
    __shared__ u16 t[32][33];
    const bool bf = is_bf16_input(probe);
    const int bid = blockIdx.x;

    if (bid < 4096) {                     // convert X (8388608 elems, exact)
        int i = (bid * 256 + threadIdx.x) * 8;
        if (bf) {
            *(u16x8*)&Xc[i] = *(const u16x8*)&((const u16*)X)[i];
        } else {
            const float* s = (const float*)X + i;
            u16x8 o;
#pragma unroll
            for (int j = 0; j < 8; j++) o[j] = f2bf(s[j]);
            *(u16x8*)&Xc[i] = o;
        }
        return;
    }

    const void* in; u16* out; int R, C, bx, by;
    if (bid < 8192) {        // Wq^T: grid 64x64
        int b2 = bid - 4096; in = Wq; out = WqkvT;
        R = 2048; C = 2048; bx = (b2 & 63) * 32; by = (b2 >> 6) * 32;
    } else if (bid < 9216) { // Wk^T: grid 16x64
        int b2 = bid - 8192; in = Wk; out = WqkvT + 2048 * 2048;
        R = 2048; C = 512; bx = (b2 & 15) * 32; by = (b2 >> 4) * 32;
    } else {                 // Wv^T: grid 16x64
        int b2 = bid - 9216; in = Wv; out = WqkvT + 2560 * 2048;
        R = 2048; C = 512; bx = (b2 & 15) * 32; by = (b2 >> 4) * 32;
    }
    int x = threadIdx.x & 31, y = threadIdx.x >> 5;
    if (bf) {
        const u16* s = (const u16*)in;
#pragma unroll
        for (int i = 0; i < 32; i += 8)
            t[y + i][x] = s[(size_t)(by + y + i) * C + bx + x];
    } else {
        const float* s = (const float*)in;
#pragma unroll
        for (int i = 0; i < 32; i += 8)
            t[y + i][x] = f2bf(s[(size_t)(by + y + i) * C + bx + x]);
    }
    __syncthreads();
#pragma unroll
    for (int i = 0; i < 32; i += 8)
        out[(size_t)(bx + y + i) * R + by + x] = t[x][y + i];
}

__global__ __launch_bounds__(256) void tconv_kernel(
    const void* __restrict__ in, u16* __restrict__ out, int R, int C,
    const unsigned* __restrict__ probe)
{
    bool bf = is_bf16_input(probe);
    __shared__ u16 t[32][33];
    int x = threadIdx.x & 31, y = threadIdx.x >> 5;
    int bx = blockIdx.x * 32, by = blockIdx.y * 32;
    if (bf) {
        const u16* s = (const u16*)in;
#pragma unroll
        for (int i = 0; i < 32; i += 8)
            t[y + i][x] = s[(size_t)(by + y + i) * C + bx + x];
    } else {
        const float* s = (const float*)in;
#pragma unroll
        for (int i = 0; i < 32; i += 8)
            t[y + i][x] = f2bf(s[(size_t)(by + y + i) * C + bx + x]);
    }
    __syncthreads();
#pragma unroll
    for (int i = 0; i < 32; i += 8)
        out[(size_t)(bx + y + i) * R + by + x] = t[x][y + i];
}

// Transpose with separate input row stride (pulls V columns out of fused QKV).
__global__ __launch_bounds__(256) void transpose_kernel(
    const u16* __restrict__ in, u16* __restrict__ out, int R, int LD)
{
    __shared__ u16 t[32][33];
    int x = threadIdx.x & 31, y = threadIdx.x >> 5;
    int bx = blockIdx.x * 32, by = blockIdx.y * 32;
#pragma unroll
    for (int i = 0; i < 32; i += 8)
        t[y + i][x] = in[(size_t)(by + y + i) * LD + bx + x];
    __syncthreads();
#pragma unroll
    for (int i = 0; i < 32; i += 8)
        out[(size_t)(bx + y + i) * R + by + x] = t[x][y + i];
}

// ---------------------------------------------------------------------------
// GEMM: C[M,N] = (A[M,K] @ BT[N,K]^T + bias[N]) * scale
// global_load_lds width=16 staging into linear [128][32] LDS tiles.
// Bias read RAW (bf16/f32 via probe); segmented for the fused-QKV call.
// ---------------------------------------------------------------------------
__global__ __launch_bounds__(256) void gemm_bias_kernel(
    const u16* __restrict__ A, const u16* __restrict__ BT,
    const void* __restrict__ bias0, const void* __restrict__ bias1,
    const void* __restrict__ bias2, void* __restrict__ Cout,
    int M, int N, int K, const unsigned* __restrict__ probe,
    int out_native, float scale)
{
    __shared__ __align__(16) u16 As[128 * 32];
    __shared__ __align__(16) u16 Bs[128 * 32];
    const int tid  = threadIdx.x;
    const int lane = tid & 63, wave = tid >> 6;
    const int quad = lane >> 4, li = lane & 15;
    const int bm = blockIdx.x * 128, bn = blockIdx.y * 128;
    const int wm = (wave >> 1) * 64, wn = (wave & 1) * 64;
    const int lrow = lane >> 2;          // 0..15 row within 16-row chunk
    const int lcol = (lane & 3) * 8;     // u16 col offset

    f32x4 acc[4][4] = {};

    for (int k0 = 0; k0 < K; k0 += 32) {
#pragma unroll
        for (int j = 0; j < 2; j++) {
            int c = wave * 2 + j;
            int row = c * 16 + lrow;
            gload16(&A [(size_t)(bm + row) * K + k0 + lcol], &As[c * 16 * 32]);
            gload16(&BT[(size_t)(bn + row) * K + k0 + lcol], &Bs[c * 16 * 32]);
        }
        __syncthreads();   // vmcnt drained at barrier: tiles ready
        bf16x8 af[4], bfr[4];
#pragma unroll
        for (int i = 0; i < 4; i++)
            af[i]  = *(const bf16x8*)&As[(wm + i * 16 + li) * 32 + quad * 8];
#pragma unroll
        for (int i = 0; i < 4; i++)
            bfr[i] = *(const bf16x8*)&Bs[(wn + i * 16 + li) * 32 + quad * 8];
#pragma unroll
        for (int mt = 0; mt < 4; mt++)
#pragma unroll
            for (int nt = 0; nt < 4; nt++)
                acc[mt][nt] = __builtin_amdgcn_mfma_f32_16x16x32_bf16(
                    af[mt], bfr[nt], acc[mt][nt], 0, 0, 0);
        __syncthreads();
    }

    const bool bf_in = is_bf16_input(probe);
    const bool out_bf = out_native ? bf_in : true;
#pragma unroll
    for (int nt = 0; nt < 4; nt++) {
        int col = bn + wn + nt * 16 + li;
        const void* bp; int bc;
        if (col < 2048)      { bp = bias0; bc = col; }
        else if (col < 2560) { bp = bias1; bc = col - 2048; }
        else                 { bp = bias2; bc = col - 2560; }
        float bb = bf_in ? bf2f(((const u16*)bp)[bc]) : ((const float*)bp)[bc];
        if (out_bf) {
            u16* C16 = (u16*)Cout;
#pragma unroll
            for (int mt = 0; mt < 4; mt++)
#pragma unroll
                for (int r = 0; r < 4; r++) {
                    int row = bm + wm + mt * 16 + quad * 4 + r;
                    C16[(size_t)row * N + col] = f2bf((acc[mt][nt][r] + bb) * scale);
                }
        } else {
            float* Cf = (float*)Cout;
#pragma unroll
            for (int mt = 0; mt < 4; mt++)
#pragma unroll
                for (int r = 0; r < 4; r++) {
                    int row = bm + wm + mt * 16 + quad * 4 + r;
                    Cf[(size_t)row * N + col] = (acc[mt][nt][r] + bb) * scale;
                }
        }
    }
}

// ---------------------------------------------------------------------------
// Flash attention v13 = round-10 body EXACTLY (V staged in LDS with the
// one-tile-ahead register prefetch), balanced split-key schedule.
// Round-11 lesson (twice-confirmed with v4): V direct-from-global puts
// ~200-400cy L2 latency on the serial softmax->PV chain; the LDS staging's
// prefetch pipeline is latency HIDING, not just bandwidth. Do not remove.
// Schedule: qt 0..6 unsplit, qt 7..13 x2 chunks, qt 14..15 x3; every unit
// <= 28 iters; grid (27,16,2) = 864 blocks, all co-resident.
// f32 partial-O: 436 units overlay dead Xc+WqkvT, 204 overlay d_out.
// Q:[B*S,3072]  K:[B*S,3072]@+2048  VT:[512,B*S]  O:[B*S,2048].
// ---------------------------------------------------------------------------
__global__ __launch_bounds__(256) void flash_kernel(
    const u16* __restrict__ Q, const u16* __restrict__ Kg,
    const u16* __restrict__ VT, u16* __restrict__ O,
    float* __restrict__ POws, float* __restrict__ POdout,
    float* __restrict__ PM, float* __restrict__ PL)
{
    constexpr int S = 2048, D = 2048, DH = 128, QKSTR = 3072;
    constexpr float SCALE = 0.08838834764831845f;  // 1/sqrt(128)
    __shared__ __align__(16) u16 Ks[32 * 136];   // [key][dh]   8704 B
    __shared__ __align__(16) u16 Vt[128 * 40];   // [dh][key]  10240 B
    __shared__ __align__(16) u16 Pw[4][32 * 40]; // [qrow][key] 10240 B

    const int tid  = threadIdx.x;
    const int wave = tid >> 6, lane = tid & 63;
    const int quad = lane >> 4, li = lane & 15;
    const int uu = blockIdx.x, h = blockIdx.y, b = blockIdx.z;
    // unit decode: uu 0..6 -> unsplit qt=uu; uu 7..20 -> qt 7..13 x2 chunks;
    // uu 21..26 -> qt 14..15 x3 chunks. Chunk = near-equal tile count.
    int qt, cc, nc;
    if (uu < 7)       { qt = uu;                         cc = 0;          nc = 1; }
    else if (uu < 21) { int t = uu - 7;  qt = 7 + (t >> 1);  cc = t & 1;  nc = 2; }
    else              { int t = uu - 21; qt = 14 + t / 3;    cc = t % 3;  nc = 3; }
    const int T = qt + 1;                 // tiles (128 keys each)
    const int tb = T / nc, trem = T % nc;
    const int tcnt = tb + (cc < trem ? 1 : 0);
    const int tstart = cc * tb + (cc < trem ? cc : trem);
    const int kstart = tstart * 128;
    const int kend   = (tstart + tcnt) * 128;
    const int g = h >> 2;
    const int q0w = qt * 128 + wave * 32;        // this wave's first q-row

    const u16* Qb = Q  + (size_t)b * S * QKSTR;
    const u16* Kb = Kg + (size_t)b * S * QKSTR;
    const u16* Vg = VT + (size_t)g * DH * (2 * S) + (size_t)b * S;

    // Q fragments: B-operand, rows q0w + m*16 + li, k = quad*8 (+c*32)
    bf16x8 qf[2][4];
#pragma unroll
    for (int m = 0; m < 2; m++)
#pragma unroll
        for (int c = 0; c < 4; c++)
            qf[m][c] = *(const bf16x8*)&Qb[(size_t)(q0w + m * 16 + li) * QKSTR
                                           + h * DH + c * 32 + quad * 8];

    f32x4 oacc[2][8] = {};
    float mr[2] = { -INFINITY, -INFINITY };
    float lr[2] = { 0.f, 0.f };

    // --- register prefetch of tile at kstart ---
    u16x8 kreg[2], vreg[2];
#pragma unroll
    for (int ch = 0; ch < 2; ch++) {
        int idx = tid + ch * 256;
        kreg[ch] = *(const u16x8*)&Kb[(size_t)(kstart + (idx >> 4)) * QKSTR
                                      + g * DH + (idx & 15) * 8];
        vreg[ch] = *(const u16x8*)&Vg[(size_t)(idx >> 2) * (2 * S)
                                      + kstart + (idx & 3) * 8];
    }

    for (int kc = kstart; kc < kend; kc += 32) {
        // commit prefetched tile to LDS
#pragma unroll
        for (int ch = 0; ch < 2; ch++) {
            int idx = tid + ch * 256;
            *(u16x8*)&Ks[(idx >> 4) * 136 + (idx & 15) * 8] = kreg[ch];
            *(u16x8*)&Vt[(idx >> 2) * 40  + (idx & 3) * 8]  = vreg[ch];
        }
        __syncthreads();

        // issue prefetch for next tile (overlaps with compute below)
        int kn = kc + 32;
        if (kn < kend) {
#pragma unroll
            for (int ch = 0; ch < 2; ch++) {
                int idx = tid + ch * 256;
                kreg[ch] = *(const u16x8*)&Kb[(size_t)(kn + (idx >> 4)) * QKSTR
                                              + g * DH + (idx & 15) * 8];
                vreg[ch] = *(const u16x8*)&Vg[(size_t)(idx >> 2) * (2 * S)
                                              + kn + (idx & 3) * 8];
            }
        }

        if (kc <= q0w) {   // causal: tiles with kc > q0w are fully masked
            // S^T = K · Q^T : sacc[m][t], C row = key (quad*4+r), col = qrow (li)
            f32x4 sacc[2][2] = {};
#pragma unroll
            for (int t = 0; t < 2; t++)
#pragma unroll
                for (int c = 0; c < 4; c++) {
                    bf16x8 kf = *(const bf16x8*)&Ks[(t * 16 + li) * 136 + c * 32 + quad * 8];
#pragma unroll
                    for (int m = 0; m < 2; m++)
                        sacc[m][t] = __builtin_amdgcn_mfma_f32_16x16x32_bf16(
                            kf, qf[m][c], sacc[m][t], 0, 0, 0);
                }

            float alpha_b[2][4];
#pragma unroll
            for (int m = 0; m < 2; m++) {
                int row = q0w + m * 16 + li;
                f32x4 s0 = sacc[m][0] * SCALE;
                f32x4 s1 = sacc[m][1] * SCALE;
#pragma unroll
                for (int r = 0; r < 4; r++) {
                    int k0 = kc + quad * 4 + r;
                    if (k0 > row)      s0[r] = -INFINITY;
                    if (k0 + 16 > row) s1[r] = -INFINITY;
                }
                float mx = fmaxf(fmaxf(fmaxf(s0[0], s0[1]), fmaxf(s0[2], s0[3])),
                                 fmaxf(fmaxf(s1[0], s1[1]), fmaxf(s1[2], s1[3])));
                mx = fmaxf(mx, __shfl_xor(mx, 16));
                mx = fmaxf(mx, __shfl_xor(mx, 32));
                float mnew = fmaxf(mr[m], mx);
                float al = __expf(mr[m] - mnew);
                mr[m] = mnew;
                f32x4 p0, p1;
                float ps = 0.f;
#pragma unroll
                for (int r = 0; r < 4; r++) {
                    p0[r] = __expf(s0[r] - mnew);
                    p1[r] = __expf(s1[r] - mnew);
                    ps += p0[r] + p1[r];
                }
                ps += __shfl_xor(ps, 16);
                ps += __shfl_xor(ps, 32);
                lr[m] = lr[m] * al + ps;
                u16x4 c0, c1;
#pragma unroll
                for (int r = 0; r < 4; r++) { c0[r] = f2bf(p0[r]); c1[r] = f2bf(p1[r]); }
                *(u16x4*)&Pw[wave][(m * 16 + li) * 40 + quad * 4]      = c0;
                *(u16x4*)&Pw[wave][(m * 16 + li) * 40 + 16 + quad * 4] = c1;
#pragma unroll
                for (int r = 0; r < 4; r++)
                    alpha_b[m][r] = __shfl(al, quad * 4 + r, 16);
            }

            // rescale O accumulators
#pragma unroll
            for (int m = 0; m < 2; m++)
#pragma unroll
                for (int dt = 0; dt < 8; dt++)
#pragma unroll
                    for (int r = 0; r < 4; r++)
                        oacc[m][dt][r] *= alpha_b[m][r];

            // drain P stores (same wave) before vector re-read
            asm volatile("s_waitcnt lgkmcnt(0)" ::: "memory");
            union { u16x8 u; bf16x8 bv; } pc0, pc1;
            pc0.u = *(const u16x8*)&Pw[wave][(0 * 16 + li) * 40 + quad * 8];
            pc1.u = *(const u16x8*)&Pw[wave][(1 * 16 + li) * 40 + quad * 8];
            bf16x8 pf[2] = { pc0.bv, pc1.bv };

            // O += P · V
#pragma unroll
            for (int dt = 0; dt < 8; dt++) {
                bf16x8 vf = *(const bf16x8*)&Vt[(dt * 16 + li) * 40 + quad * 8];
#pragma unroll
                for (int m = 0; m < 2; m++)
                    oacc[m][dt] = __builtin_amdgcn_mfma_f32_16x16x32_bf16(
                        pf[m], vf, oacc[m][dt], 0, 0, 0);
            }
        }
        __syncthreads();
    }

    if (nc == 1) {
        u16* Ob = O + (size_t)b * S * D;
#pragma unroll
        for (int m = 0; m < 2; m++) {
#pragma unroll
            for (int r = 0; r < 4; r++) {
                float linv = 1.0f / __shfl(lr[m], quad * 4 + r, 16);
                int row = q0w + m * 16 + quad * 4 + r;
#pragma unroll
                for (int dt = 0; dt < 8; dt++)
                    Ob[(size_t)row * D + h * DH + dt * 16 + li] =
                        f2bf(oacc[m][dt][r] * linv);
            }
        }
    } else {
        // partial epilogue: unnormalized O (f32) + per-row m, l.
        // punit local layout: qt 7..13 -> (qt-7)*2+cc (0..13);
        //                     qt 14..15 -> 14+(qt-14)*3+cc (14..19).
        const int pl = (qt <= 13) ? (qt - 7) * 2 + cc : 14 + (qt - 14) * 3 + cc;
        const int pg = (b * 16 + h) * 20 + pl;
        float* POu = (pg < POWS_UNITS)
                   ? (POws   + (size_t)pg * 16384)
                   : (POdout + (size_t)(pg - POWS_UNITS) * 16384);
#pragma unroll
        for (int m = 0; m < 2; m++)
#pragma unroll
            for (int r = 0; r < 4; r++) {
                int rl = wave * 32 + m * 16 + quad * 4 + r;
#pragma unroll
                for (int dt = 0; dt < 8; dt++)
                    POu[rl * 128 + dt * 16 + li] = oacc[m][dt][r];
            }
        if (quad == 0) {
#pragma unroll
            for (int m = 0; m < 2; m++) {
                int rl = wave * 32 + m * 16 + li;   // mr/lr are per-li rows
                PM[pg * 128 + rl] = mr[m];
                PL[pg * 128 + rl] = lr[m];
            }
        }
    }
}

// ---------------------------------------------------------------------------
// Merge the nc key-chunk partials of each split q-tile (qt 7..15):
// O = sum_i e^{m_i-M} O_i / sum_i e^{m_i-M} l_i.
// Grid (9, 16, 2) x 256 thr; thread -> (row = t>>1, col-half = (t&1)*64).
// ---------------------------------------------------------------------------
__global__ __launch_bounds__(256) void combine_kernel(
    const float* __restrict__ POws, const float* __restrict__ POdout,
    const float* __restrict__ PM, const float* __restrict__ PL,
    u16* __restrict__ O)
{
    constexpr int S = 2048, D = 2048;
    const int qt = 7 + blockIdx.x, h = blockIdx.y, b = blockIdx.z;
    const int nc = (qt <= 13) ? 2 : 3;
    const int pl0 = (qt <= 13) ? (qt - 7) * 2 : 14 + (qt - 14) * 3;
    const int pg0 = (b * 16 + h) * 20 + pl0;
    const int t = threadIdx.x;
    const int row = t >> 1, half = (t & 1) * 64;

    float m[3], l[3], w[3];
    const float* p[3];
    float M = -INFINITY;
    for (int i = 0; i < nc; i++) {
        int pg = pg0 + i;
        m[i] = PM[pg * 128 + row];
        l[i] = PL[pg * 128 + row];
        M = fmaxf(M, m[i]);
        p[i] = ((pg < POWS_UNITS)
                ? (POws   + (size_t)pg * 16384)
                : (POdout + (size_t)(pg - POWS_UNITS) * 16384))
               + row * 128 + half;
    }
    float lsum = 0.f;
    for (int i = 0; i < nc; i++) { w[i] = __expf(m[i] - M); lsum += w[i] * l[i]; }
    float linv = 1.0f / lsum;

    u16* out = O + (size_t)(b * S + qt * 128 + row) * D + h * 128 + half;
#pragma unroll 4
    for (int j = 0; j < 64; j += 4) {
        f32x4 acc = {};
        for (int i = 0; i < nc; i++) {
            f32x4 a = *(const f32x4*)&p[i][j];
#pragma unroll
            for (int e = 0; e < 4; e++) acc[e] += a[e] * w[i];
        }
        u16x4 o;
#pragma unroll
        for (int e = 0; e < 4; e++) o[e] = f2bf(acc[e] * linv);
        *(u16x4*)&out[j] = o;
    }
}

// ---------------------------------------------------------------------------
extern "C" void kernel_launch(void* const* d_in, const int* in_sizes, int n_in,
                              void* d_out, int out_size, void* d_ws, size_t ws_size,
                              hipStream_t stream)
{
    const void* X  = d_in[0];
    const void* Wq = d_in[3];
    const void* bq = d_in[4];
    const void* Wk = d_in[5];
    const void* bk = d_in[6];
    const void* Wv = d_in[7];
    const void* bv = d_in[8];
    const void* Wo = d_in[9];
    const void* bo = d_in[10];
    const unsigned* probe = (const unsigned*)d_in[3];

    u16* ws    = (u16*)d_ws;
    u16* Xc    = ws;                     // [0, 8388608)        X bf16
    u16* WqkvT = Xc    + 8388608;        // [8388608, 14680064) Wqkv^T / later WoT
    u16* QKV   = WqkvT + 6291456;        // [14680064, 27262976)
    u16* VTb   = QKV   + 12582912;       // [27262976, 29360128)
    u16* Ob    = VTb   + 2097152;        // [29360128, 37748736)
    // f32 partials overlay DEAD regions during flash+combine:
    //   POws: 436 units x 16384 f32 in the dead Xc+WqkvT region (7.14M f32)
    //   PM/PL: 640x128 f32 each, after POws (still inside the dead region)
    //   POdout: 204 units x 16384 f32 overlay d_out (written only by the
    //           final GEMM, which runs after combine; fits even bf16 output)
    float* POws   = (float*)ws;
    float* PM     = POws + (size_t)POWS_UNITS * 16384;
    float* PL     = PM + 640 * 128;
    float* POdout = (float*)d_out;

    // Merged prep: convert X + transpose Wq/Wk/Wv (one launch, 10240 blocks)
    prep_kernel<<<10240, 256, 0, stream>>>(X, Xc, Wq, Wk, Wv, WqkvT, probe);

    // Fused QKV projection: grid (32,24) = 768 blocks = 3 blocks/CU.
    gemm_bias_kernel<<<dim3(32, 24), 256, 0, stream>>>(
        Xc, WqkvT, bq, bk, bv, QKV, 4096, 3072, 2048, probe, 0, 1.0f);

    // V columns (2560..3071) of QKV -> VT[512][4096]
    transpose_kernel<<<dim3(16, 128), 256, 0, stream>>>(QKV + 2560, VTb, 4096, 3072);

    // Balanced split-key flash: 27 units x 16 heads x 2 batches = 864 blocks.
    flash_kernel<<<dim3(27, 16, 2), 256, 0, stream>>>(
        QKV, QKV + 2048, VTb, Ob, POws, POdout, PM, PL);

    // Merge split q-tiles (qt 7..15; reads partials, writes Ob).
    combine_kernel<<<dim3(9, 16, 2), 256, 0, stream>>>(POws, POdout, PM, PL, Ob);

    // Wo^T into WqkvT region (partials dead after combine).
    tconv_kernel<<<dim3(64, 64), 256, 0, stream>>>(Wo, WqkvT, 2048, 2048, probe);

    gemm_bias_kernel<<<dim3(32, 16), 256, 0, stream>>>(
        Ob, WqkvT, bo, bo, bo, d_out, 4096, 2048, 2048, probe, 1, 1.0f);
}